// Round 1
// baseline (1032.323 us; speedup 1.0000x reference)
//
#include <hip/hip_runtime.h>
#include <hip/hip_bf16.h>

// ---------------- problem constants ----------------
constexpr int GT = 32768;          // B*T frames
constexpr int BATCH = 1024;
constexpr int TSEQ = 32;

// ---------------- workspace layout (floats) ----------------
// R0 [0, 13107200): obsT [400][GT]; later reused: pool2 [128][GT] @0, y1 [128][GT] @4194304
// R1 [13107200, 26214400): pool1 [400][GT]; later reused: featsT [64][GT]
constexpr size_t OBS_T = 0;
constexpr size_t POOL1 = 13107200;
constexpr size_t POOL2 = 0;
constexpr size_t Y1    = 4194304;
constexpr size_t FEATS = 13107200;
constexpr size_t WB    = 26214400;          // weights region
constexpr size_t W_C1  = WB + 0;            // 576   : conv1 wT [36][16]
constexpr size_t W_C2  = WB + 576;          // 4608  : conv2 wT [144][32]
constexpr size_t W_F1  = WB + 5184;         // 16384 : fc1 wT [128][128], BN folded
constexpr size_t B_F1  = WB + 21568;        // 128
constexpr size_t W_F2  = WB + 21696;        // 8192  : fc2 wT [128][64], BN folded
constexpr size_t B_F2  = WB + 29888;        // 64
constexpr size_t W_ENC = WB + 29952;        // 98304 : enc wT [192][512], rows r=u*4+gate
constexpr size_t B_ENC = WB + 128256;       // 512
constexpr size_t W_DEC = WB + 128768;       // 65536 : (dec_w_ih+dec_w_hh) wT [128][512]
constexpr size_t B_DEC = WB + 194304;       // 512
constexpr size_t HA    = WB + 194816;       // 131072 : h ping
constexpr size_t HB    = HA + 131072;       // 131072 : h pong
constexpr size_t CC    = HB + 131072;       // 131072 : c state
// total = 26,802,432 floats = ~107.2 MB

__device__ __forceinline__ float sigf(float x)  { return 1.f / (1.f + __expf(-x)); }
__device__ __forceinline__ float tanhfast(float x) { return 1.f - 2.f / (__expf(2.f * x) + 1.f); }

// ---------------- setup: zero state + transpose/fold weights ----------------
__global__ __launch_bounds__(256) void k_setup(
    const float* __restrict__ c1w, const float* __restrict__ c2w,
    const float* __restrict__ f1w, const float* __restrict__ f1b,
    const float* __restrict__ g1, const float* __restrict__ be1,
    const float* __restrict__ m1, const float* __restrict__ v1,
    const float* __restrict__ f2w, const float* __restrict__ f2b,
    const float* __restrict__ g2, const float* __restrict__ be2,
    const float* __restrict__ m2, const float* __restrict__ v2,
    const float* __restrict__ ewih, const float* __restrict__ ewhh, const float* __restrict__ eb,
    const float* __restrict__ dwih, const float* __restrict__ dwhh, const float* __restrict__ db,
    float* __restrict__ ws) {
  long i = (long)blockIdx.x * 256 + threadIdx.x;
  if (i < 393216) { ws[HA + i] = 0.f; return; }          // zero hA, hB, c
  i -= 393216;
  if (i < 576)  { int c = i & 15, r = i >> 4; ws[W_C1 + i] = c1w[c * 36 + r]; return; }
  i -= 576;
  if (i < 4608) { int c = i & 31, r = i >> 5; ws[W_C2 + i] = c2w[c * 144 + r]; return; }
  i -= 4608;
  if (i < 16384) { int j = i & 127, k = i >> 7;
    float s = g1[j] * rsqrtf(v1[j] + 1e-5f);
    ws[W_F1 + i] = f1w[j * 128 + k] * s; return; }
  i -= 16384;
  if (i < 128) { int j = i; float s = g1[j] * rsqrtf(v1[j] + 1e-5f);
    ws[B_F1 + i] = (f1b[j] - m1[j]) * s + be1[j]; return; }
  i -= 128;
  if (i < 8192) { int j = i & 63, k = i >> 6;
    float s = g2[j] * rsqrtf(v2[j] + 1e-5f);
    ws[W_F2 + i] = f2w[j * 128 + k] * s; return; }
  i -= 8192;
  if (i < 64) { int j = i; float s = g2[j] * rsqrtf(v2[j] + 1e-5f);
    ws[B_F2 + i] = (f2b[j] - m2[j]) * s + be2[j]; return; }
  i -= 64;
  if (i < 98304) { int r = i & 511, k = i >> 9;
    int u = r >> 2, gt = r & 3, jr = gt * 128 + u;
    ws[W_ENC + i] = (k < 64) ? ewih[jr * 64 + k] : ewhh[jr * 128 + (k - 64)]; return; }
  i -= 98304;
  if (i < 512) { int u = i >> 2, gt = i & 3; ws[B_ENC + i] = eb[gt * 128 + u]; return; }
  i -= 512;
  if (i < 65536) { int r = i & 511, k = i >> 9;
    int u = r >> 2, gt = r & 3, jr = gt * 128 + u;
    ws[W_DEC + i] = dwih[jr * 128 + k] + dwhh[jr * 128 + k]; return; }
  i -= 65536;
  if (i < 512) { int u = i >> 2, gt = i & 3; ws[B_DEC + i] = db[gt * 128 + u]; return; }
}

// ---------------- transpose obs [b][t][p] -> obsT [p][t][b] ----------------
__global__ __launch_bounds__(256) void k_transpose(const float* __restrict__ obs,
                                                   float* __restrict__ obsT) {
  __shared__ float tile[64][65];
  int tp0 = blockIdx.x * 64;        // 200 tiles over tp=12800
  int b0  = blockIdx.y * 64;        // 16 tiles over b=1024
  int lane = threadIdx.x & 63;
  int grp  = threadIdx.x >> 6;      // 0..3
  for (int rr = 0; rr < 16; ++rr) {
    int row = grp * 16 + rr;        // b_local
    tile[row][lane] = obs[(size_t)(b0 + row) * 12800 + tp0 + lane];
  }
  __syncthreads();
  for (int cc = 0; cc < 16; ++cc) {
    int col = grp * 16 + cc;        // tp_local
    int tp = tp0 + col;
    int t = tp / 400, p = tp % 400;
    obsT[(size_t)p * GT + t * 1024 + b0 + lane] = tile[lane][col];
  }
}

// ---------------- conv1 (4->16, 3x3 SAME on 10x10) + relu + maxpool2 ----------------
__global__ __launch_bounds__(256) void k_conv1(const float* __restrict__ obsT,
                                               const float* __restrict__ wT,
                                               const float* __restrict__ bias,
                                               float* __restrict__ pool1) {
  int g = blockIdx.x * 256 + threadIdx.x;
  int pos = blockIdx.y;                 // 0..24 pooled position
  int py = pos / 5, px = pos % 5;
  float acc[4][16];
  #pragma unroll
  for (int s = 0; s < 4; ++s)
    #pragma unroll
    for (int c = 0; c < 16; ++c) acc[s][c] = 0.f;

  for (int ci = 0; ci < 4; ++ci) {
    #pragma unroll
    for (int ky = 0; ky < 3; ++ky) {
      #pragma unroll
      for (int kx = 0; kx < 3; ++kx) {
        const float* w = wT + ((ci * 9 + ky * 3 + kx) << 4);
        float wv[16];
        #pragma unroll
        for (int c = 0; c < 16; ++c) wv[c] = w[c];
        #pragma unroll
        for (int dy = 0; dy < 2; ++dy) {
          int iy = 2 * py + dy + ky - 1;
          if ((unsigned)iy < 10u) {
            #pragma unroll
            for (int dx = 0; dx < 2; ++dx) {
              int ix = 2 * px + dx + kx - 1;
              if ((unsigned)ix < 10u) {
                float xv = obsT[(size_t)(ci * 100 + iy * 10 + ix) * GT + g];
                #pragma unroll
                for (int c = 0; c < 16; ++c)
                  acc[dy * 2 + dx][c] = fmaf(wv[c], xv, acc[dy * 2 + dx][c]);
              }
            }
          }
        }
      }
    }
  }
  #pragma unroll
  for (int c = 0; c < 16; ++c) {
    float m = fmaxf(fmaxf(acc[0][c], acc[1][c]), fmaxf(acc[2][c], acc[3][c]));
    m = fmaxf(m + bias[c], 0.f);
    pool1[(size_t)(c * 25 + pos) * GT + g] = m;
  }
}

// ---------------- conv2 (16->32, 3x3 SAME on 5x5) + relu + maxpool2(floor) ----------------
__global__ __launch_bounds__(256) void k_conv2(const float* __restrict__ pool1,
                                               const float* __restrict__ wT,
                                               const float* __restrict__ bias,
                                               float* __restrict__ pool2) {
  int g = blockIdx.x * 256 + threadIdx.x;
  int pos = blockIdx.y & 3;             // pooled pos (2x2)
  int h = blockIdx.y >> 2;              // c_out half
  int py = pos >> 1, px = pos & 1;
  float acc[4][16];
  #pragma unroll
  for (int s = 0; s < 4; ++s)
    #pragma unroll
    for (int c = 0; c < 16; ++c) acc[s][c] = 0.f;

  for (int ci = 0; ci < 16; ++ci) {
    #pragma unroll
    for (int ky = 0; ky < 3; ++ky) {
      #pragma unroll
      for (int kx = 0; kx < 3; ++kx) {
        const float* w = wT + (ci * 9 + ky * 3 + kx) * 32 + h * 16;
        float wv[16];
        #pragma unroll
        for (int c = 0; c < 16; ++c) wv[c] = w[c];
        #pragma unroll
        for (int dy = 0; dy < 2; ++dy) {
          int iy = 2 * py + dy + ky - 1;
          if ((unsigned)iy < 5u) {
            #pragma unroll
            for (int dx = 0; dx < 2; ++dx) {
              int ix = 2 * px + dx + kx - 1;
              if ((unsigned)ix < 5u) {
                float xv = pool1[(size_t)(ci * 25 + iy * 5 + ix) * GT + g];
                #pragma unroll
                for (int c = 0; c < 16; ++c)
                  acc[dy * 2 + dx][c] = fmaf(wv[c], xv, acc[dy * 2 + dx][c]);
              }
            }
          }
        }
      }
    }
  }
  #pragma unroll
  for (int c = 0; c < 16; ++c) {
    float m = fmaxf(fmaxf(acc[0][c], acc[1][c]), fmaxf(acc[2][c], acc[3][c]));
    m = fmaxf(m + bias[h * 16 + c], 0.f);
    int cp2 = (h * 16 + c) * 4 + pos;   // torch NCHW flatten: c*4 + py*2 + px
    pool2[(size_t)cp2 * GT + g] = m;
  }
}

// ---------------- FC (+folded BN) + relu, 16 outputs/thread ----------------
__global__ __launch_bounds__(256) void k_fc16(const float* __restrict__ x,
                                              const float* __restrict__ WT,
                                              const float* __restrict__ bf,
                                              float* __restrict__ y, int K, int J) {
  int g = blockIdx.x * 256 + threadIdx.x;
  int j0 = blockIdx.y * 16;
  float acc[16];
  #pragma unroll
  for (int c = 0; c < 16; ++c) acc[c] = 0.f;
  for (int k = 0; k < K; ++k) {
    float xv = x[(size_t)k * GT + g];
    const float* w = WT + (size_t)k * J + j0;
    #pragma unroll
    for (int c = 0; c < 16; ++c) acc[c] = fmaf(w[c], xv, acc[c]);
  }
  #pragma unroll
  for (int c = 0; c < 16; ++c)
    y[(size_t)(j0 + c) * GT + g] = fmaxf(acc[c] + bf[j0 + c], 0.f);
}

// ---------------- encoder LSTM step ----------------
// gates rows permuted r=u*4+gate; thread owns 8 rows = 2 complete units.
__global__ __launch_bounds__(256) void k_enc_step(const float* __restrict__ feats,
                                                  const float* __restrict__ WT,
                                                  const float* __restrict__ br,
                                                  const float* __restrict__ hPrev,
                                                  float* __restrict__ hNext,
                                                  float* __restrict__ cbuf, int t) {
  int b = blockIdx.x * 256 + threadIdx.x;   // grid.x = 4
  int r0 = blockIdx.y * 8;                  // grid.y = 64
  float acc[8];
  #pragma unroll
  for (int i = 0; i < 8; ++i) acc[i] = br[r0 + i];
  const float* xcol = feats + (size_t)t * 1024 + b;
  for (int k = 0; k < 64; ++k) {
    float xv = xcol[(size_t)k * GT];
    const float* w = WT + k * 512 + r0;
    #pragma unroll
    for (int i = 0; i < 8; ++i) acc[i] = fmaf(w[i], xv, acc[i]);
  }
  for (int k = 0; k < 128; ++k) {
    float hv = hPrev[k * 1024 + b];
    const float* w = WT + (64 + k) * 512 + r0;
    #pragma unroll
    for (int i = 0; i < 8; ++i) acc[i] = fmaf(w[i], hv, acc[i]);
  }
  #pragma unroll
  for (int uu = 0; uu < 2; ++uu) {
    int u = (r0 >> 2) + uu;
    float iv = acc[uu * 4 + 0], fv = acc[uu * 4 + 1];
    float gv = acc[uu * 4 + 2], ov = acc[uu * 4 + 3];
    float co = cbuf[u * 1024 + b];
    float cn = sigf(fv) * co + sigf(iv) * tanhfast(gv);
    float hn = sigf(ov) * tanhfast(cn);
    cbuf[u * 1024 + b] = cn;
    hNext[u * 1024 + b] = hn;
  }
}

// ---------------- decoder LSTM step (x_in == h  =>  W = W_ih + W_hh) ----------------
__global__ __launch_bounds__(256) void k_dec_step(const float* __restrict__ WT,
                                                  const float* __restrict__ br,
                                                  const float* __restrict__ hPrev,
                                                  float* __restrict__ hNext,
                                                  float* __restrict__ cbuf) {
  int b = blockIdx.x * 256 + threadIdx.x;
  int r0 = blockIdx.y * 8;
  float acc[8];
  #pragma unroll
  for (int i = 0; i < 8; ++i) acc[i] = br[r0 + i];
  for (int k = 0; k < 128; ++k) {
    float hv = hPrev[k * 1024 + b];
    const float* w = WT + k * 512 + r0;
    #pragma unroll
    for (int i = 0; i < 8; ++i) acc[i] = fmaf(w[i], hv, acc[i]);
  }
  #pragma unroll
  for (int uu = 0; uu < 2; ++uu) {
    int u = (r0 >> 2) + uu;
    float iv = acc[uu * 4 + 0], fv = acc[uu * 4 + 1];
    float gv = acc[uu * 4 + 2], ov = acc[uu * 4 + 3];
    float co = cbuf[u * 1024 + b];
    float cn = sigf(fv) * co + sigf(iv) * tanhfast(gv);
    float hn = sigf(ov) * tanhfast(cn);
    cbuf[u * 1024 + b] = cn;
    hNext[u * 1024 + b] = hn;
  }
}

// ---------------- output head: pred[b][t][o] = h . out_w[o] + out_b[o] ----------------
__global__ __launch_bounds__(256) void k_out(const float* __restrict__ h,
                                             const float* __restrict__ ow,
                                             const float* __restrict__ ob,
                                             float* __restrict__ out, int tdec) {
  int idx = blockIdx.x * 256 + threadIdx.x;   // 12288 = 12 * 1024
  int b = idx & 1023;
  int o = idx >> 10;
  float acc = ob[o];
  for (int k = 0; k < 128; ++k)
    acc = fmaf(ow[o * 128 + k], h[k * 1024 + b], acc);
  out[b * 120 + tdec * 12 + o] = acc;
}

// ---------------- launch ----------------
extern "C" void kernel_launch(void* const* d_in, const int* in_sizes, int n_in,
                              void* d_out, int out_size, void* d_ws, size_t ws_size,
                              hipStream_t stream) {
  const float* obs  = (const float*)d_in[0];
  const float* c1w  = (const float*)d_in[1];
  const float* c1b  = (const float*)d_in[2];
  const float* c2w  = (const float*)d_in[3];
  const float* c2b  = (const float*)d_in[4];
  const float* f1w  = (const float*)d_in[5];
  const float* f1b  = (const float*)d_in[6];
  const float* g1   = (const float*)d_in[7];
  const float* be1  = (const float*)d_in[8];
  const float* m1   = (const float*)d_in[9];
  const float* v1   = (const float*)d_in[10];
  const float* f2w  = (const float*)d_in[11];
  const float* f2b  = (const float*)d_in[12];
  const float* g2   = (const float*)d_in[13];
  const float* be2  = (const float*)d_in[14];
  const float* m2   = (const float*)d_in[15];
  const float* v2   = (const float*)d_in[16];
  const float* ewih = (const float*)d_in[17];
  const float* ewhh = (const float*)d_in[18];
  const float* eb   = (const float*)d_in[19];
  const float* dwih = (const float*)d_in[20];
  const float* dwhh = (const float*)d_in[21];
  const float* db   = (const float*)d_in[22];
  const float* ow   = (const float*)d_in[23];
  const float* ob   = (const float*)d_in[24];
  float* ws  = (float*)d_ws;
  float* out = (float*)d_out;

  // weight prep + state zeroing
  k_setup<<<2297, 256, 0, stream>>>(c1w, c2w, f1w, f1b, g1, be1, m1, v1,
                                    f2w, f2b, g2, be2, m2, v2,
                                    ewih, ewhh, eb, dwih, dwhh, db, ws);
  // obs -> frame-last layout
  k_transpose<<<dim3(200, 16), 256, 0, stream>>>(obs, ws + OBS_T);
  // CNN
  k_conv1<<<dim3(128, 25), 256, 0, stream>>>(ws + OBS_T, ws + W_C1, c1b, ws + POOL1);
  k_conv2<<<dim3(128, 8), 256, 0, stream>>>(ws + POOL1, ws + W_C2, c2b, ws + POOL2);
  // FC1 + BN + relu ; FC2 + BN + relu
  k_fc16<<<dim3(128, 8), 256, 0, stream>>>(ws + POOL2, ws + W_F1, ws + B_F1, ws + Y1, 128, 128);
  k_fc16<<<dim3(128, 4), 256, 0, stream>>>(ws + Y1, ws + W_F2, ws + B_F2, ws + FEATS, 128, 64);
  // encoder: 32 steps, ping-pong h
  float* hA = ws + HA;
  float* hB = ws + HB;
  float* cb = ws + CC;
  float* hp = hA;
  float* hn = hB;
  for (int t = 0; t < TSEQ; ++t) {
    k_enc_step<<<dim3(4, 64), 256, 0, stream>>>(ws + FEATS, ws + W_ENC, ws + B_ENC, hp, hn, cb, t);
    float* tmp = hp; hp = hn; hn = tmp;
  }
  // after 32 steps, h_n is in hp (== hA), c_n in cb
  for (int t = 0; t < 10; ++t) {
    k_dec_step<<<dim3(4, 64), 256, 0, stream>>>(ws + W_DEC, ws + B_DEC, hp, hn, cb);
    k_out<<<48, 256, 0, stream>>>(hn, ow, ob, out, t);
    float* tmp = hp; hp = hn; hn = tmp;
  }
}

// Round 2
// 927.287 us; speedup vs baseline: 1.1133x; 1.1133x over previous
//
#include <hip/hip_runtime.h>
#include <hip/hip_bf16.h>

// ---------------- problem constants ----------------
constexpr int GT = 32768;          // B*T frames
constexpr int TSEQ = 32;

// ---------------- workspace layout (floats) ----------------
// R0 [0, 13107200): obsT [400][GT]; reused: pool2 [128][GT]@0, y1 [128][GT]@4194304;
//                   after fc2 reused again: gates_x slices t=0..24 (25 x 524288 = 13107200 exactly)
// R1 [13107200, 26214400): pool1 [400][GT]; reused: featsT [64][GT]@13107200,
//                   gates_x slices t=25..31 @ 15204352 (7 x 524288 = 3670016)
constexpr size_t OBS_T = 0;
constexpr size_t POOL1 = 13107200;
constexpr size_t POOL2 = 0;
constexpr size_t Y1    = 4194304;
constexpr size_t FEATS = 13107200;
constexpr size_t GX0   = 0;                 // t<25
constexpr size_t GX1   = 15204352;          // t>=25
constexpr size_t WB    = 26214400;          // weights region
constexpr size_t W_C1  = WB + 0;            // 576   : conv1 wT [36][16]
constexpr size_t W_C2  = WB + 576;          // 4608  : conv2 wT [144][32]
constexpr size_t W_F1  = WB + 5184;         // 16384 : fc1 wT [128][128], BN folded
constexpr size_t B_F1  = WB + 21568;        // 128
constexpr size_t W_F2  = WB + 21696;        // 8192  : fc2 wT [128][64], BN folded
constexpr size_t B_F2  = WB + 29888;        // 64
constexpr size_t W_ENC = WB + 29952;        // 98304 : enc wT [192][512], rows r=u*4+gate
constexpr size_t B_ENC = WB + 128256;       // 512
constexpr size_t W_DEC = WB + 128768;       // 65536 : (dec_w_ih+dec_w_hh) wT [128][512]
constexpr size_t B_DEC = WB + 194304;       // 512
constexpr size_t HA    = WB + 194816;       // 131072 : h ping
constexpr size_t HB    = HA + 131072;       // 131072 : h pong
constexpr size_t CC    = HB + 131072;       // 131072 : c state
// total = 26,802,432 floats = ~107.2 MB (same as R1 kernel)

__device__ __forceinline__ float sigf(float x)  { return 1.f / (1.f + __expf(-x)); }
__device__ __forceinline__ float tanhfast(float x) { return 1.f - 2.f / (__expf(2.f * x) + 1.f); }

// ---------------- setup: zero state + transpose/fold weights ----------------
__global__ __launch_bounds__(256) void k_setup(
    const float* __restrict__ c1w, const float* __restrict__ c2w,
    const float* __restrict__ f1w, const float* __restrict__ f1b,
    const float* __restrict__ g1, const float* __restrict__ be1,
    const float* __restrict__ m1, const float* __restrict__ v1,
    const float* __restrict__ f2w, const float* __restrict__ f2b,
    const float* __restrict__ g2, const float* __restrict__ be2,
    const float* __restrict__ m2, const float* __restrict__ v2,
    const float* __restrict__ ewih, const float* __restrict__ ewhh, const float* __restrict__ eb,
    const float* __restrict__ dwih, const float* __restrict__ dwhh, const float* __restrict__ db,
    float* __restrict__ ws) {
  long i = (long)blockIdx.x * 256 + threadIdx.x;
  if (i < 393216) { ws[HA + i] = 0.f; return; }          // zero hA, hB, c
  i -= 393216;
  if (i < 576)  { int c = i & 15, r = i >> 4; ws[W_C1 + i] = c1w[c * 36 + r]; return; }
  i -= 576;
  if (i < 4608) { int c = i & 31, r = i >> 5; ws[W_C2 + i] = c2w[c * 144 + r]; return; }
  i -= 4608;
  if (i < 16384) { int j = i & 127, k = i >> 7;
    float s = g1[j] * rsqrtf(v1[j] + 1e-5f);
    ws[W_F1 + i] = f1w[j * 128 + k] * s; return; }
  i -= 16384;
  if (i < 128) { int j = i; float s = g1[j] * rsqrtf(v1[j] + 1e-5f);
    ws[B_F1 + i] = (f1b[j] - m1[j]) * s + be1[j]; return; }
  i -= 128;
  if (i < 8192) { int j = i & 63, k = i >> 6;
    float s = g2[j] * rsqrtf(v2[j] + 1e-5f);
    ws[W_F2 + i] = f2w[j * 128 + k] * s; return; }
  i -= 8192;
  if (i < 64) { int j = i; float s = g2[j] * rsqrtf(v2[j] + 1e-5f);
    ws[B_F2 + i] = (f2b[j] - m2[j]) * s + be2[j]; return; }
  i -= 64;
  if (i < 98304) { int r = i & 511, k = i >> 9;
    int u = r >> 2, gt = r & 3, jr = gt * 128 + u;
    ws[W_ENC + i] = (k < 64) ? ewih[jr * 64 + k] : ewhh[jr * 128 + (k - 64)]; return; }
  i -= 98304;
  if (i < 512) { int u = i >> 2, gt = i & 3; ws[B_ENC + i] = eb[gt * 128 + u]; return; }
  i -= 512;
  if (i < 65536) { int r = i & 511, k = i >> 9;
    int u = r >> 2, gt = r & 3, jr = gt * 128 + u;
    ws[W_DEC + i] = dwih[jr * 128 + k] + dwhh[jr * 128 + k]; return; }
  i -= 65536;
  if (i < 512) { int u = i >> 2, gt = i & 3; ws[B_DEC + i] = db[gt * 128 + u]; return; }
}

// ---------------- transpose obs [b][tp] -> obsT [p][t][b], float4 loads ----------------
__global__ __launch_bounds__(256) void k_transpose(const float* __restrict__ obs,
                                                   float* __restrict__ obsT) {
  __shared__ float tile[64][65];
  int tp0 = blockIdx.x * 64;        // 200 tiles over tp=12800
  int b0  = blockIdx.y * 64;        // 16 tiles over b=1024
  int q     = threadIdx.x & 15;     // tp quad
  int rbase = threadIdx.x >> 4;     // 0..15
  #pragma unroll
  for (int rr = 0; rr < 4; ++rr) {
    int row = rbase + rr * 16;      // b_local 0..63
    const float4 v = *(const float4*)(obs + (size_t)(b0 + row) * 12800 + tp0 + q * 4);
    tile[row][q * 4 + 0] = v.x;
    tile[row][q * 4 + 1] = v.y;
    tile[row][q * 4 + 2] = v.z;
    tile[row][q * 4 + 3] = v.w;
  }
  __syncthreads();
  int lane = threadIdx.x & 63;
  int grp  = threadIdx.x >> 6;      // 0..3
  for (int cc = 0; cc < 16; ++cc) {
    int col = grp * 16 + cc;        // tp_local
    int tp = tp0 + col;
    int t = tp / 400, p = tp % 400;
    obsT[(size_t)p * GT + t * 1024 + b0 + lane] = tile[lane][col];
  }
}

// ---------------- conv1 (4->16, 3x3 SAME on 10x10) + relu + maxpool2 ----------------
// patch-in-registers: 16 loads per ci (wave-uniform bounds), branch-free FMAs
__global__ __launch_bounds__(256) void k_conv1(const float* __restrict__ obsT,
                                               const float* __restrict__ wT,
                                               const float* __restrict__ bias,
                                               float* __restrict__ pool1) {
  int g = blockIdx.x * 256 + threadIdx.x;
  int pos = blockIdx.y;                 // 0..24 pooled position
  int py = pos / 5, px = pos % 5;
  float acc[4][16];
  #pragma unroll
  for (int s = 0; s < 4; ++s)
    #pragma unroll
    for (int c = 0; c < 16; ++c) acc[s][c] = 0.f;

  #pragma unroll 1
  for (int ci = 0; ci < 4; ++ci) {
    float p[16];
    #pragma unroll
    for (int r = 0; r < 4; ++r) {
      int iy = 2 * py + r - 1;
      #pragma unroll
      for (int cx = 0; cx < 4; ++cx) {
        int ix = 2 * px + cx - 1;
        bool ok = ((unsigned)iy < 10u) && ((unsigned)ix < 10u);   // wave-uniform
        p[r * 4 + cx] = ok ? obsT[(size_t)(ci * 100 + iy * 10 + ix) * GT + g] : 0.f;
      }
    }
    #pragma unroll
    for (int t9 = 0; t9 < 9; ++t9) {
      int ky = t9 / 3, kx = t9 % 3;
      const float* w = wT + ((ci * 9 + t9) << 4);
      float wv[16];
      #pragma unroll
      for (int c = 0; c < 16; ++c) wv[c] = w[c];
      #pragma unroll
      for (int dy = 0; dy < 2; ++dy)
        #pragma unroll
        for (int dx = 0; dx < 2; ++dx) {
          float xv = p[(dy + ky) * 4 + (dx + kx)];
          #pragma unroll
          for (int c = 0; c < 16; ++c)
            acc[dy * 2 + dx][c] = fmaf(wv[c], xv, acc[dy * 2 + dx][c]);
        }
    }
  }
  #pragma unroll
  for (int c = 0; c < 16; ++c) {
    float m = fmaxf(fmaxf(acc[0][c], acc[1][c]), fmaxf(acc[2][c], acc[3][c]));
    m = fmaxf(m + bias[c], 0.f);
    pool1[(size_t)(c * 25 + pos) * GT + g] = m;
  }
}

// ---------------- conv2 (16->32, 3x3 SAME on 5x5) + relu + maxpool2(floor) ----------------
__global__ __launch_bounds__(256) void k_conv2(const float* __restrict__ pool1,
                                               const float* __restrict__ wT,
                                               const float* __restrict__ bias,
                                               float* __restrict__ pool2) {
  int g = blockIdx.x * 256 + threadIdx.x;
  int pos = blockIdx.y & 3;             // pooled pos (2x2)
  int h = blockIdx.y >> 2;              // c_out half
  int py = pos >> 1, px = pos & 1;
  float acc[4][16];
  #pragma unroll
  for (int s = 0; s < 4; ++s)
    #pragma unroll
    for (int c = 0; c < 16; ++c) acc[s][c] = 0.f;

  #pragma unroll 1
  for (int ci = 0; ci < 16; ++ci) {
    float p[16];
    #pragma unroll
    for (int r = 0; r < 4; ++r) {
      int iy = 2 * py + r - 1;
      #pragma unroll
      for (int cx = 0; cx < 4; ++cx) {
        int ix = 2 * px + cx - 1;
        bool ok = ((unsigned)iy < 5u) && ((unsigned)ix < 5u);     // wave-uniform
        p[r * 4 + cx] = ok ? pool1[(size_t)(ci * 25 + iy * 5 + ix) * GT + g] : 0.f;
      }
    }
    #pragma unroll
    for (int t9 = 0; t9 < 9; ++t9) {
      int ky = t9 / 3, kx = t9 % 3;
      const float* w = wT + (ci * 9 + t9) * 32 + h * 16;
      float wv[16];
      #pragma unroll
      for (int c = 0; c < 16; ++c) wv[c] = w[c];
      #pragma unroll
      for (int dy = 0; dy < 2; ++dy)
        #pragma unroll
        for (int dx = 0; dx < 2; ++dx) {
          float xv = p[(dy + ky) * 4 + (dx + kx)];
          #pragma unroll
          for (int c = 0; c < 16; ++c)
            acc[dy * 2 + dx][c] = fmaf(wv[c], xv, acc[dy * 2 + dx][c]);
        }
    }
  }
  #pragma unroll
  for (int c = 0; c < 16; ++c) {
    float m = fmaxf(fmaxf(acc[0][c], acc[1][c]), fmaxf(acc[2][c], acc[3][c]));
    m = fmaxf(m + bias[h * 16 + c], 0.f);
    int cp2 = (h * 16 + c) * 4 + pos;   // torch NCHW flatten: c*4 + py*2 + px
    pool2[(size_t)cp2 * GT + g] = m;
  }
}

// ---------------- FC (+folded BN) + relu, 16 outputs/thread ----------------
__global__ __launch_bounds__(256) void k_fc16(const float* __restrict__ x,
                                              const float* __restrict__ WT,
                                              const float* __restrict__ bf,
                                              float* __restrict__ y, int K, int J) {
  int g = blockIdx.x * 256 + threadIdx.x;
  int j0 = blockIdx.y * 16;
  float acc[16];
  #pragma unroll
  for (int c = 0; c < 16; ++c) acc[c] = 0.f;
  for (int k = 0; k < K; ++k) {
    float xv = x[(size_t)k * GT + g];
    const float* w = WT + (size_t)k * J + j0;
    #pragma unroll
    for (int c = 0; c < 16; ++c) acc[c] = fmaf(w[c], xv, acc[c]);
  }
  #pragma unroll
  for (int c = 0; c < 16; ++c)
    y[(size_t)(j0 + c) * GT + g] = fmaxf(acc[c] + bf[j0 + c], 0.f);
}

// ---------------- encoder x-projection for ALL timesteps (parallel, bias folded) ----
// gx[t][r][b] = b_enc[r] + sum_k feats[k][t*1024+b] * W_ENC[k][r],  k in [0,64)
__global__ __launch_bounds__(256) void k_xgates(const float* __restrict__ feats,
                                                const float* __restrict__ WT,
                                                const float* __restrict__ br,
                                                float* __restrict__ gx0,
                                                float* __restrict__ gx1) {
  int t  = blockIdx.x >> 2;
  int bq = blockIdx.x & 3;
  int b  = bq * 256 + threadIdx.x;
  int r0 = blockIdx.y * 32;
  float acc[32];
  #pragma unroll
  for (int i = 0; i < 32; ++i) acc[i] = br[r0 + i];
  const float* xcol = feats + (size_t)t * 1024 + b;
  for (int k = 0; k < 64; ++k) {
    float xv = xcol[(size_t)k * GT];
    const float* w = WT + k * 512 + r0;
    #pragma unroll
    for (int i = 0; i < 32; ++i) acc[i] = fmaf(w[i], xv, acc[i]);
  }
  float* gxs = (t < 25) ? (gx0 + (size_t)t * 524288)
                        : (gx1 + (size_t)(t - 25) * 524288);
  #pragma unroll
  for (int i = 0; i < 32; ++i) gxs[(size_t)(r0 + i) * 1024 + b] = acc[i];
}

// ---------------- encoder LSTM step (h-part only, K=128) ----------------
__global__ __launch_bounds__(256) void k_enc_step(const float* __restrict__ gx,
                                                  const float* __restrict__ WT,
                                                  const float* __restrict__ hPrev,
                                                  float* __restrict__ hNext,
                                                  float* __restrict__ cbuf) {
  int b = blockIdx.x * 256 + threadIdx.x;   // grid.x = 4
  int r0 = blockIdx.y * 8;                  // grid.y = 64
  float acc[8];
  #pragma unroll
  for (int i = 0; i < 8; ++i) acc[i] = gx[(size_t)(r0 + i) * 1024 + b];
  for (int k = 0; k < 128; ++k) {
    float hv = hPrev[k * 1024 + b];
    const float* w = WT + (64 + k) * 512 + r0;
    #pragma unroll
    for (int i = 0; i < 8; ++i) acc[i] = fmaf(w[i], hv, acc[i]);
  }
  #pragma unroll
  for (int uu = 0; uu < 2; ++uu) {
    int u = (r0 >> 2) + uu;
    float iv = acc[uu * 4 + 0], fv = acc[uu * 4 + 1];
    float gv = acc[uu * 4 + 2], ov = acc[uu * 4 + 3];
    float co = cbuf[u * 1024 + b];
    float cn = sigf(fv) * co + sigf(iv) * tanhfast(gv);
    float hn = sigf(ov) * tanhfast(cn);
    cbuf[u * 1024 + b] = cn;
    hNext[u * 1024 + b] = hn;
  }
}

// ---------------- decoder LSTM step + fused output head for PREVIOUS h ----------------
// blockIdx.y < 64 : normal step (x_in == h  =>  W = W_ih + W_hh)
// blockIdx.y == 64: output head for hPrev (tprev), runs concurrently
__global__ __launch_bounds__(256) void k_dec_step(const float* __restrict__ WT,
                                                  const float* __restrict__ br,
                                                  const float* __restrict__ hPrev,
                                                  float* __restrict__ hNext,
                                                  float* __restrict__ cbuf,
                                                  const float* __restrict__ ow,
                                                  const float* __restrict__ ob,
                                                  float* __restrict__ out, int tprev) {
  int b = blockIdx.x * 256 + threadIdx.x;
  if (blockIdx.y == 64) {
    if (tprev < 0) return;
    float acc[12];
    #pragma unroll
    for (int o = 0; o < 12; ++o) acc[o] = ob[o];
    for (int k = 0; k < 128; ++k) {
      float hv = hPrev[k * 1024 + b];
      #pragma unroll
      for (int o = 0; o < 12; ++o) acc[o] = fmaf(ow[o * 128 + k], hv, acc[o]);
    }
    #pragma unroll
    for (int o = 0; o < 12; ++o) out[b * 120 + tprev * 12 + o] = acc[o];
    return;
  }
  int r0 = blockIdx.y * 8;
  float acc[8];
  #pragma unroll
  for (int i = 0; i < 8; ++i) acc[i] = br[r0 + i];
  for (int k = 0; k < 128; ++k) {
    float hv = hPrev[k * 1024 + b];
    const float* w = WT + k * 512 + r0;
    #pragma unroll
    for (int i = 0; i < 8; ++i) acc[i] = fmaf(w[i], hv, acc[i]);
  }
  #pragma unroll
  for (int uu = 0; uu < 2; ++uu) {
    int u = (r0 >> 2) + uu;
    float iv = acc[uu * 4 + 0], fv = acc[uu * 4 + 1];
    float gv = acc[uu * 4 + 2], ov = acc[uu * 4 + 3];
    float co = cbuf[u * 1024 + b];
    float cn = sigf(fv) * co + sigf(iv) * tanhfast(gv);
    float hn = sigf(ov) * tanhfast(cn);
    cbuf[u * 1024 + b] = cn;
    hNext[u * 1024 + b] = hn;
  }
}

// ---------------- final output head (t = 9) ----------------
__global__ __launch_bounds__(256) void k_out12(const float* __restrict__ h,
                                               const float* __restrict__ ow,
                                               const float* __restrict__ ob,
                                               float* __restrict__ out, int tdec) {
  int b = blockIdx.x * 256 + threadIdx.x;
  float acc[12];
  #pragma unroll
  for (int o = 0; o < 12; ++o) acc[o] = ob[o];
  for (int k = 0; k < 128; ++k) {
    float hv = h[k * 1024 + b];
    #pragma unroll
    for (int o = 0; o < 12; ++o) acc[o] = fmaf(ow[o * 128 + k], hv, acc[o]);
  }
  #pragma unroll
  for (int o = 0; o < 12; ++o) out[b * 120 + tdec * 12 + o] = acc[o];
}

// ---------------- launch ----------------
extern "C" void kernel_launch(void* const* d_in, const int* in_sizes, int n_in,
                              void* d_out, int out_size, void* d_ws, size_t ws_size,
                              hipStream_t stream) {
  const float* obs  = (const float*)d_in[0];
  const float* c1w  = (const float*)d_in[1];
  const float* c1b  = (const float*)d_in[2];
  const float* c2w  = (const float*)d_in[3];
  const float* c2b  = (const float*)d_in[4];
  const float* f1w  = (const float*)d_in[5];
  const float* f1b  = (const float*)d_in[6];
  const float* g1   = (const float*)d_in[7];
  const float* be1  = (const float*)d_in[8];
  const float* m1   = (const float*)d_in[9];
  const float* v1   = (const float*)d_in[10];
  const float* f2w  = (const float*)d_in[11];
  const float* f2b  = (const float*)d_in[12];
  const float* g2   = (const float*)d_in[13];
  const float* be2  = (const float*)d_in[14];
  const float* m2   = (const float*)d_in[15];
  const float* v2   = (const float*)d_in[16];
  const float* ewih = (const float*)d_in[17];
  const float* ewhh = (const float*)d_in[18];
  const float* eb   = (const float*)d_in[19];
  const float* dwih = (const float*)d_in[20];
  const float* dwhh = (const float*)d_in[21];
  const float* db   = (const float*)d_in[22];
  const float* ow   = (const float*)d_in[23];
  const float* ob   = (const float*)d_in[24];
  float* ws  = (float*)d_ws;
  float* out = (float*)d_out;

  // weight prep + state zeroing
  k_setup<<<2297, 256, 0, stream>>>(c1w, c2w, f1w, f1b, g1, be1, m1, v1,
                                    f2w, f2b, g2, be2, m2, v2,
                                    ewih, ewhh, eb, dwih, dwhh, db, ws);
  // obs -> frame-last layout
  k_transpose<<<dim3(200, 16), 256, 0, stream>>>(obs, ws + OBS_T);
  // CNN
  k_conv1<<<dim3(128, 25), 256, 0, stream>>>(ws + OBS_T, ws + W_C1, c1b, ws + POOL1);
  k_conv2<<<dim3(128, 8), 256, 0, stream>>>(ws + POOL1, ws + W_C2, c2b, ws + POOL2);
  // FC1 + BN + relu ; FC2 + BN + relu
  k_fc16<<<dim3(128, 8), 256, 0, stream>>>(ws + POOL2, ws + W_F1, ws + B_F1, ws + Y1, 128, 128);
  k_fc16<<<dim3(128, 4), 256, 0, stream>>>(ws + Y1, ws + W_F2, ws + B_F2, ws + FEATS, 128, 64);
  // encoder x-projection for all 32 timesteps (parallel)
  k_xgates<<<dim3(128, 16), 256, 0, stream>>>(ws + FEATS, ws + W_ENC, ws + B_ENC,
                                              ws + GX0, ws + GX1);
  // encoder: 32 steps (K=128 h-recurrence only), ping-pong h
  float* hA = ws + HA;
  float* hB = ws + HB;
  float* cb = ws + CC;
  float* hp = hA;
  float* hn = hB;
  for (int t = 0; t < TSEQ; ++t) {
    const float* gxs = (t < 25) ? (ws + GX0 + (size_t)t * 524288)
                                : (ws + GX1 + (size_t)(t - 25) * 524288);
    k_enc_step<<<dim3(4, 64), 256, 0, stream>>>(gxs, ws + W_ENC, hp, hn, cb);
    float* tmp = hp; hp = hn; hn = tmp;
  }
  // decoder: 10 steps; output head for step t-1 fused as blockIdx.y==64
  for (int t = 0; t < 10; ++t) {
    k_dec_step<<<dim3(4, 65), 256, 0, stream>>>(ws + W_DEC, ws + B_DEC, hp, hn, cb,
                                                ow, ob, out, t - 1);
    float* tmp = hp; hp = hn; hn = tmp;
  }
  k_out12<<<4, 256, 0, stream>>>(hp, ow, ob, out, 9);
}